// Round 3
// baseline (652.386 us; speedup 1.0000x reference)
//
#include <hip/hip_runtime.h>
#include <cstdint>

typedef __attribute__((ext_vector_type(8))) __bf16 bf16x8;
typedef __attribute__((ext_vector_type(4))) float f32x4;
typedef __attribute__((ext_vector_type(8))) unsigned short u16x8;

__device__ __forceinline__ unsigned short f2bf(float f) {
  unsigned u = __float_as_uint(f);
  unsigned r = (u + 0x7FFFu + ((u >> 16) & 1u)) >> 16;  // RNE
  return (unsigned short)r;
}
__device__ __forceinline__ float bf2f(unsigned short u) {
  return __uint_as_float(((unsigned)u) << 16);
}

__device__ __forceinline__ __attribute__((address_space(3))) void* to_lds(void* p) {
  return (__attribute__((address_space(3))) void*)p;
}
__device__ __forceinline__ const __attribute__((address_space(1))) void* to_glb(const void* p) {
  return (const __attribute__((address_space(1))) void*)p;
}

// ---------------- transpose: fp32 in[R,C] -> bf16 out[C,R] ----------------
__global__ void k_transpose_bf16(const float* __restrict__ in, unsigned short* __restrict__ out,
                                 int R, int C) {
  __shared__ float tile[32][33];
  int c0 = blockIdx.x * 32, r0 = blockIdx.y * 32;
  int tx = threadIdx.x, ty = threadIdx.y;  // block (32,8)
  #pragma unroll
  for (int i = 0; i < 32; i += 8)
    tile[ty + i][tx] = in[(size_t)(r0 + ty + i) * C + c0 + tx];
  __syncthreads();
  #pragma unroll
  for (int i = 0; i < 32; i += 8)
    out[(size_t)(c0 + ty + i) * R + r0 + tx] = f2bf(tile[tx][ty + i]);
}

// ---------------- fp32 -> bf16 contiguous ----------------
__global__ void k_convert_bf16(const float4* __restrict__ in, ushort4* __restrict__ out, int n4) {
  int i = blockIdx.x * blockDim.x + threadIdx.x;
  if (i < n4) {
    float4 v = in[i];
    ushort4 o; o.x = f2bf(v.x); o.y = f2bf(v.y); o.z = f2bf(v.z); o.w = f2bf(v.w);
    out[i] = o;
  }
}

__global__ void k_concat_bias(const float* __restrict__ b0, const float* __restrict__ b1,
                              float* __restrict__ bc) {
  int i = blockIdx.x * blockDim.x + threadIdx.x;
  if (i < 2048) bc[i] = (i < 1024) ? b0[i] : b1[i - 1024];
}

// ---------------- KV fp32 [512,2048] -> Kn bf16 [512,1024] (l2-normalized),
//                  Vt bf16 [1024,512] (V^T), Vb bf16 [512,1024] ----------------
__global__ void k_post_kv(const float4* __restrict__ KV, unsigned short* __restrict__ Kn,
                          unsigned short* __restrict__ Vt, unsigned short* __restrict__ Vb) {
  int row = blockIdx.x;   // 512
  int tid = threadIdx.x;  // 256
  const float4* r = KV + (size_t)row * 512;
  float4 k4 = r[tid];
  float4 v4 = r[256 + tid];
  float s = k4.x * k4.x + k4.y * k4.y + k4.z * k4.z + k4.w * k4.w;
  #pragma unroll
  for (int m = 32; m; m >>= 1) s += __shfl_xor(s, m, 64);
  __shared__ float red[4];
  if ((tid & 63) == 0) red[tid >> 6] = s;
  __syncthreads();
  float tot = red[0] + red[1] + red[2] + red[3];
  float inv = 1.0f / fmaxf(sqrtf(tot), 1e-12f);
  ushort4 o; o.x = f2bf(k4.x * inv); o.y = f2bf(k4.y * inv);
  o.z = f2bf(k4.z * inv); o.w = f2bf(k4.w * inv);
  *(ushort4*)(Kn + (size_t)row * 1024 + tid * 4) = o;
  ushort4 ov; ov.x = f2bf(v4.x); ov.y = f2bf(v4.y); ov.z = f2bf(v4.z); ov.w = f2bf(v4.w);
  *(ushort4*)(Vb + (size_t)row * 1024 + tid * 4) = ov;
  int vc = tid * 4;
  Vt[(size_t)(vc + 0) * 512 + row] = ov.x;
  Vt[(size_t)(vc + 1) * 512 + row] = ov.y;
  Vt[(size_t)(vc + 2) * 512 + row] = ov.z;
  Vt[(size_t)(vc + 3) * 512 + row] = ov.w;
}

// ---------------- softmax with per-row temperature, bf16 in/out ----------------
// w = softmax(S_raw * alpha_row), alpha_row = (1/32) * rsqrt(norm2[row]).
__global__ void k_softmax(const unsigned short* __restrict__ S, const float* __restrict__ norm2,
                          unsigned short* __restrict__ W) {
  int tid = threadIdx.x;
  int wv = tid >> 6, lane = tid & 63;
  int row = blockIdx.x * 4 + wv;
  float alpha = 0.03125f * rsqrtf(fmaxf(norm2[row], 1e-24f));
  u16x8 u = *(const u16x8*)(S + (size_t)row * 512 + lane * 8);
  float v[8];
  #pragma unroll
  for (int i = 0; i < 8; ++i) v[i] = bf2f(u[i]) * alpha;
  float m = v[0];
  #pragma unroll
  for (int i = 1; i < 8; ++i) m = fmaxf(m, v[i]);
  #pragma unroll
  for (int o = 32; o; o >>= 1) m = fmaxf(m, __shfl_xor(m, o, 64));
  float s = 0.f;
  #pragma unroll
  for (int i = 0; i < 8; ++i) { v[i] = __expf(v[i] - m); s += v[i]; }
  #pragma unroll
  for (int o = 32; o; o >>= 1) s += __shfl_xor(s, o, 64);
  float inv = 1.0f / s;
  u16x8 ou;
  #pragma unroll
  for (int i = 0; i < 8; ++i) ou[i] = f2bf(v[i] * inv);
  *(u16x8*)(W + (size_t)row * 512 + lane * 8) = ou;
}

// ---------------- bf16 MFMA GEMM: C[M,N] = A[M,K] * B^T stored as [N,K] ----------------
// 128x128 tile, 4 waves 2x2, BK=64, 16x16x32 MFMA, XOR-swizzled LDS chunks,
// global_load_lds width 16, XCD-aware tile remap (gridDim.y % 8 == 0).
// MODE 0: C fp32 = acc*scale + bias[gc].
// MODE 2: Cb bf16 = acc*scale (+ bias[gc] if bias).
// MODE 4: Cb bf16 transposed: Cb[gc*ldcb+gr] = acc.
// MODE 5: stacked [Q|L]: gc<1024 -> Cb(Qb)=acc+bias[gc] + norm2 atomics;
//         gc>=1024 -> Cb2(Lb)=acc+bias[gc].
// MODE 6: gate: g = sigmoid(acc + Lb[t,d]); C fp32 = g*Xb + (1-g)*Rb.
template <int MODE>
__global__ __launch_bounds__(256, 2) void k_gemm(
    const unsigned short* __restrict__ A, int lda,
    const unsigned short* __restrict__ B, int ldb,
    const float* __restrict__ bias, float scale,
    float* __restrict__ C, int ldc,
    unsigned short* __restrict__ Cb, int ldcb,
    unsigned short* __restrict__ Cb2,
    const unsigned short* __restrict__ auxL,
    const unsigned short* __restrict__ auxX,
    const unsigned short* __restrict__ auxR,
    float* __restrict__ Cnorm,
    int K) {
  __shared__ __align__(16) unsigned short As[128 * 64];
  __shared__ __align__(16) unsigned short Bs[128 * 64];
  const int tid = threadIdx.x;
  const int lane = tid & 63, w = tid >> 6;

  int mt, nt;
  {
    int f = blockIdx.y * gridDim.x + blockIdx.x;
    int NTg = gridDim.x, MTg = gridDim.y;
    if ((MTg & 7) == 0) {
      int xcd = f & 7;
      int j = f >> 3;
      nt = j % NTg;
      mt = (j / NTg) * 8 + xcd;
    } else {
      mt = blockIdx.y; nt = blockIdx.x;
    }
  }
  const int m0 = mt * 128, n0 = nt * 128;

  const int srow = lane >> 3;
  const int schunk = (lane & 7) ^ srow;
  const unsigned short* gA = A + (size_t)(m0 + w * 8 + srow) * lda + schunk * 8;
  const unsigned short* gB = B + (size_t)(n0 + w * 8 + srow) * ldb + schunk * 8;
  unsigned short* lA = As + (w * 8) * 64;
  unsigned short* lB = Bs + (w * 8) * 64;

  f32x4 acc[4][4];
  f32x4 zero = {0.f, 0.f, 0.f, 0.f};
  #pragma unroll
  for (int i = 0; i < 4; ++i)
    #pragma unroll
    for (int j = 0; j < 4; ++j) acc[i][j] = zero;

  const int fr = lane & 15, q = lane >> 4;
  const int wr = (w >> 1) * 64, wc = (w & 1) * 64;

  for (int k0 = 0; k0 < K; k0 += 64) {
    #pragma unroll
    for (int i = 0; i < 4; ++i) {
      __builtin_amdgcn_global_load_lds(to_glb(gA + (size_t)i * 32 * lda + k0),
                                       to_lds(lA + i * 32 * 64), 16, 0, 0);
      __builtin_amdgcn_global_load_lds(to_glb(gB + (size_t)i * 32 * ldb + k0),
                                       to_lds(lB + i * 32 * 64), 16, 0, 0);
    }
    __syncthreads();
    #pragma unroll
    for (int ks = 0; ks < 2; ++ks) {
      bf16x8 af[4], bfr[4];
      const int p = (ks * 4 + q) ^ (lane & 7);
      #pragma unroll
      for (int mi = 0; mi < 4; ++mi) {
        af[mi] = *(const bf16x8*)(As + (wr + mi * 16 + fr) * 64 + p * 8);
        bfr[mi] = *(const bf16x8*)(Bs + (wc + mi * 16 + fr) * 64 + p * 8);
      }
      #pragma unroll
      for (int mi = 0; mi < 4; ++mi)
        #pragma unroll
        for (int ni = 0; ni < 4; ++ni)
          acc[mi][ni] = __builtin_amdgcn_mfma_f32_16x16x32_bf16(af[mi], bfr[ni], acc[mi][ni], 0, 0, 0);
    }
    __syncthreads();
  }

  if (MODE == 5 && n0 < 1024) {
    // Q side: bf16 store + per-row sum-of-squares for deferred l2-norm
    #pragma unroll
    for (int mi = 0; mi < 4; ++mi) {
      float s2[4] = {0.f, 0.f, 0.f, 0.f};
      #pragma unroll
      for (int ni = 0; ni < 4; ++ni) {
        const int gc = n0 + wc + ni * 16 + fr;
        const float bv = bias[gc];
        #pragma unroll
        for (int r = 0; r < 4; ++r) {
          const int gr = m0 + wr + mi * 16 + q * 4 + r;
          float c = acc[mi][ni][r] + bv;
          Cb[(size_t)gr * ldcb + gc] = f2bf(c);
          s2[r] += c * c;
        }
      }
      #pragma unroll
      for (int r = 0; r < 4; ++r) {
        float v = s2[r];
        v += __shfl_xor(v, 1, 64);
        v += __shfl_xor(v, 2, 64);
        v += __shfl_xor(v, 4, 64);
        v += __shfl_xor(v, 8, 64);
        if (fr == 0) atomicAdd(Cnorm + (m0 + wr + mi * 16 + q * 4 + r), v);
      }
    }
  } else {
    #pragma unroll
    for (int ni = 0; ni < 4; ++ni) {
      const int gc = n0 + wc + ni * 16 + fr;
      const float bv = (MODE == 4 || MODE == 6) ? 0.0f : (bias ? bias[gc] : 0.0f);
      #pragma unroll
      for (int mi = 0; mi < 4; ++mi) {
        #pragma unroll
        for (int r = 0; r < 4; ++r) {
          const int gr = m0 + wr + mi * 16 + q * 4 + r;
          if (MODE == 0) {
            C[(size_t)gr * ldc + gc] = acc[mi][ni][r] * scale + bv;
          } else if (MODE == 2) {
            Cb[(size_t)gr * ldcb + gc] = f2bf(acc[mi][ni][r] * scale + bv);
          } else if (MODE == 4) {
            Cb[(size_t)gc * ldcb + gr] = f2bf(acc[mi][ni][r]);
          } else if (MODE == 5) {
            Cb2[(size_t)gr * 1024 + (gc - 1024)] = f2bf(acc[mi][ni][r] + bv);
          } else {  // MODE 6
            const size_t idx = (size_t)gr * 1024 + gc;
            float l = bf2f(auxL[idx]);
            float g = 1.0f / (1.0f + __expf(-(acc[mi][ni][r] + l)));
            float x = bf2f(auxX[idx]);
            float rr = bf2f(auxR[idx]);
            C[idx] = g * x + (1.0f - g) * rr;
          }
        }
      }
    }
  }
}

extern "C" void kernel_launch(void* const* d_in, const int* in_sizes, int n_in,
                              void* d_out, int out_size, void* d_ws, size_t ws_size,
                              hipStream_t stream) {
  const float* X   = (const float*)d_in[0];
  const float* mem = (const float*)d_in[1];
  const float* Wq  = (const float*)d_in[2];
  const float* bq  = (const float*)d_in[3];
  const float* Wk  = (const float*)d_in[4];
  const float* bk  = (const float*)d_in[5];
  const float* Wv  = (const float*)d_in[6];
  const float* bv  = (const float*)d_in[7];
  const float* Wg  = (const float*)d_in[8];
  const float* bg  = (const float*)d_in[9];
  float* out = (float*)d_out;

  const int T = 32768, D = 1024, NS = 512;

  char* p = (char*)d_ws;
  auto alloc = [&](size_t b) { char* r = p; p += (b + 255) & ~(size_t)255; return r; };
  unsigned short* WB    = (unsigned short*)alloc((size_t)2 * D * D * 2);  // [WqT; WgxT] [2048,1024]
  unsigned short* WkvT  = (unsigned short*)alloc((size_t)2 * D * D * 2);  // [WkT; WvT] [2048,1024]
  unsigned short* WgrT  = (unsigned short*)alloc((size_t)D * D * 2);      // Wg bottom-half^T [1024,1024]
  unsigned short* memb  = (unsigned short*)alloc((size_t)NS * D * 2);
  float*          bkv   = (float*)alloc((size_t)2 * D * 4);
  float*          bqg   = (float*)alloc((size_t)2 * D * 4);
  float*          KV    = (float*)alloc((size_t)NS * 2 * D * 4);
  unsigned short* Kn    = (unsigned short*)alloc((size_t)NS * D * 2);
  unsigned short* Vt    = (unsigned short*)alloc((size_t)D * NS * 2);     // V^T [1024,512]
  unsigned short* Vb    = (unsigned short*)alloc((size_t)NS * D * 2);     // V [512,1024]
  unsigned short* VgT   = (unsigned short*)alloc((size_t)D * NS * 2);     // (V@Wg_r)^T [1024,512]
  unsigned short* Xb    = (unsigned short*)alloc((size_t)T * D * 2);      // X bf16
  unsigned short* Qb    = (unsigned short*)alloc((size_t)T * D * 2);      // Q bf16 (unnormalized)
  unsigned short* Lb    = (unsigned short*)alloc((size_t)T * D * 2);      // X@Wg_x + bg, bf16
  unsigned short* Sb    = (unsigned short*)alloc((size_t)T * NS * 2);     // raw scores bf16
  unsigned short* Wsm   = (unsigned short*)alloc((size_t)T * NS * 2);     // softmax weights bf16
  unsigned short* Rb    = (unsigned short*)alloc((size_t)T * D * 2);      // R bf16
  float*          norm2 = (float*)alloc((size_t)T * 4);

  hipMemsetAsync(norm2, 0, (size_t)T * 4, stream);

  // --- prep ---
  k_transpose_bf16<<<dim3(32, 32), dim3(32, 8), 0, stream>>>(Wq, WB, D, D);
  k_transpose_bf16<<<dim3(32, 32), dim3(32, 8), 0, stream>>>(Wg, WB + (size_t)D * D, D, D);           // top half of Wg
  k_transpose_bf16<<<dim3(32, 32), dim3(32, 8), 0, stream>>>(Wg + (size_t)D * D, WgrT, D, D);         // bottom half
  k_transpose_bf16<<<dim3(32, 32), dim3(32, 8), 0, stream>>>(Wk, WkvT, D, D);
  k_transpose_bf16<<<dim3(32, 32), dim3(32, 8), 0, stream>>>(Wv, WkvT + (size_t)D * D, D, D);
  k_convert_bf16<<<512, 256, 0, stream>>>((const float4*)mem, (ushort4*)memb, NS * D / 4);
  k_concat_bias<<<8, 256, 0, stream>>>(bk, bv, bkv);
  k_concat_bias<<<8, 256, 0, stream>>>(bq, bg, bqg);
  k_convert_bf16<<<T * D / 4 / 256, 256, 0, stream>>>((const float4*)X, (ushort4*)Xb, T * D / 4);

  // --- K,V: [512,2048] = memb @ [Wk|Wv] + [bk|bv] ---
  k_gemm<0><<<dim3(16, 4), 256, 0, stream>>>(
      memb, D, WkvT, D, bkv, 1.0f, KV, 2 * D, nullptr, 0, nullptr, nullptr, nullptr, nullptr, nullptr, D);
  k_post_kv<<<NS, 256, 0, stream>>>((const float4*)KV, Kn, Vt, Vb);

  // --- Vg^T = (V @ Wg_r)^T, transposed-write GEMM (tiny) ---
  k_gemm<4><<<dim3(8, 4), 256, 0, stream>>>(
      Vb, D, WgrT, D, nullptr, 1.0f, nullptr, 0, VgT, NS, nullptr, nullptr, nullptr, nullptr, nullptr, D);

  // --- [Q|L] = Xb @ [WqT;WgxT] + [bq|bg]: Qb + norm2, Lb ---
  k_gemm<5><<<dim3(16, 256), 256, 0, stream>>>(
      Xb, D, WB, D, bqg, 1.0f, nullptr, 0, Qb, D, Lb, nullptr, nullptr, nullptr, norm2, D);

  // --- raw scores = Qb @ Kn^T -> bf16 (temperature + norm applied in softmax) ---
  k_gemm<2><<<dim3(4, 256), 256, 0, stream>>>(
      Qb, D, Kn, D, nullptr, 1.0f, nullptr, 0, Sb, NS, nullptr, nullptr, nullptr, nullptr, nullptr, D);
  k_softmax<<<T / 4, 256, 0, stream>>>(Sb, norm2, Wsm);

  // --- R = w @ V -> bf16 ---
  k_gemm<2><<<dim3(8, 256), 256, 0, stream>>>(
      Wsm, NS, Vt, NS, nullptr, 1.0f, nullptr, 0, Rb, D, nullptr, nullptr, nullptr, nullptr, nullptr, NS);

  // --- gate: L2 = w @ Vg; g = sigmoid(L + L2); out = g*x + (1-g)*r ---
  k_gemm<6><<<dim3(8, 256), 256, 0, stream>>>(
      Wsm, NS, VgT, NS, nullptr, 1.0f, out, D, nullptr, 0, nullptr, Lb, Xb, Rb, nullptr, NS);

  (void)in_sizes; (void)n_in; (void)out_size; (void)ws_size;
}